// Round 11
// baseline (1656.293 us; speedup 1.0000x reference)
//
#include <hip/hip_runtime.h>
#include <hip/hip_bf16.h>
#include <math.h>

// Problem constants (B=8, H=W=256, K=11 taps, thresh 0.2)
#define HH 256
#define WW 256
#define HW (HH*WW)
#define BB 8

typedef __hip_bfloat16 bf16;
typedef __attribute__((ext_vector_type(8))) short short8;   // 8 bf16 (4 VGPRs)
typedef __attribute__((ext_vector_type(4))) float f32x4;    // MFMA acc

// Slab: [(ROWS+2) rows][66 px][CHUNK ch] bf16. XOR swizzle with
// SLOTS = CHUNK/8 16B-slots per pixel: slot s holds channel-octet
// seg = s ^ (px & (SLOTS-1)). Both staging writes (unit-linear) and b128
// A-reads (slot = koct ^ (px&(SLOTS-1))) hit every 4-bank group exactly
// 8x per wave64 access = conflict-free minimum.

// ---------------------------------------------------------------------------
// Weight reorder: OIHW f32 -> [t][co][ci] bf16 (t = ky*3+kx)
// ---------------------------------------------------------------------------
template<int CO, int CI>
__global__ __launch_bounds__(256) void reorder_w(const float* __restrict__ w,
                                                 bf16* __restrict__ wr)
{
    int idx = blockIdx.x * 256 + threadIdx.x;
    if (idx >= 9 * CO * CI) return;
    int ci = idx % CI;
    int co = (idx / CI) % CO;
    int t  = idx / (CI * CO);
    wr[idx] = __float2bfloat16(w[((size_t)co * CI + ci) * 9 + t]);
}

// Both head weights -> one [9][32][64] bf16 buffer: co 0..10 = wh, 16..26 = wv.
__global__ __launch_bounds__(256) void reorder_w_head2(const float* __restrict__ wh,
                                                       const float* __restrict__ wv,
                                                       bf16* __restrict__ wr)
{
    int idx = blockIdx.x * 256 + threadIdx.x;
    if (idx >= 9 * 32 * 64) return;
    int ci = idx % 64;
    int co = (idx / 64) % 32;
    int t  = idx / (64 * 32);
    const float* src = (co < 16) ? wh : wv;
    int c = co & 15;
    float v = (c < 11) ? src[((size_t)c * 64 + ci) * 9 + t] : 0.0f;
    wr[idx] = __float2bfloat16(v);
}

// ---------------------------------------------------------------------------
// Vector-load staging of one CHUNK-ch chunk into the XOR-swizzled slab.
// OOB lanes write zero.
// ---------------------------------------------------------------------------
template<int CIN, int CHUNK, int ROWS, int TPB>
__device__ __forceinline__ void stage_slab(const bf16* __restrict__ in_i,
                                           bf16* __restrict__ slab,
                                           int tid, int x0, int y0, int k0)
{
    constexpr int SLOTS = CHUNK / 8;
    constexpr int UNITS = (ROWS + 2) * 66 * SLOTS;
    const short8 z8 = {0,0,0,0,0,0,0,0};
    for (int e = tid; e < UNITS; e += TPB) {
        int row = e / (66 * SLOTS), rem = e - row * (66 * SLOTS);
        int px = rem / SLOTS, slot = rem % SLOTS;
        int seg = slot ^ (px & (SLOTS - 1));
        int yy = y0 - 1 + row, xx = x0 - 1 + px;
        short8 v = z8;
        if (yy >= 0 && yy < HH && xx >= 0 && xx < WW)
            v = *(const short8*)(in_i + ((size_t)(yy * WW + xx)) * CIN + k0 + seg * 8);
        *(short8*)(slab + (size_t)e * 8) = v;
    }
}

// ---------------------------------------------------------------------------
// conv1: 3x3 conv over concat(rgb,depth) [4ch f32 planar], ReLU,
// output NHWC bf16 [G][HW][64]. blockIdx.y = img*64 + ytile.
// ---------------------------------------------------------------------------
template<int COC>
__global__ __launch_bounds__(256) void conv3x3_first(const float* __restrict__ rgb,
                                                     const float* __restrict__ depth,
                                                     const float* __restrict__ w,
                                                     const float* __restrict__ bias,
                                                     bf16* __restrict__ out, int b0)
{
    const int tid = threadIdx.x;
    const int img = blockIdx.y >> 6;
    const int b   = b0 + img;
    const int x = blockIdx.x * 64 + (tid & 63);
    const int y = (blockIdx.y & 63) * 4 + (tid >> 6);
    const int cog = blockIdx.z * COC;

    const bool vy0 = (y > 0), vy2 = (y < HH - 1);
    const bool vx0 = (x > 0), vx2 = (x < WW - 1);
    bool val[9];
    int  off[9];
    {
        int t = 0;
        for (int dy = -1; dy <= 1; ++dy)
            for (int dx = -1; dx <= 1; ++dx) {
                val[t] = (dy < 0 ? vy0 : (dy > 0 ? vy2 : true)) &&
                         (dx < 0 ? vx0 : (dx > 0 ? vx2 : true));
                off[t] = dy * WW + dx;
                ++t;
            }
    }

    float acc[COC];
#pragma unroll
    for (int j = 0; j < COC; ++j) acc[j] = bias[cog + j];

    const int p0 = y * WW + x;
#pragma unroll
    for (int ci = 0; ci < 4; ++ci) {
        const float* p = (ci < 3) ? (rgb + ((size_t)(b * 3 + ci)) * HW + p0)
                                  : (depth + (size_t)b * HW + p0);
        float v[9];
#pragma unroll
        for (int t = 0; t < 9; ++t)
            v[t] = val[t] ? p[off[t]] : 0.0f;

        const float* wp = w + ((size_t)cog * 4 + ci) * 9;
#pragma unroll
        for (int j = 0; j < COC; ++j) {
            const float* wj = wp + (size_t)j * 4 * 9;
#pragma unroll
            for (int t = 0; t < 9; ++t)
                acc[j] = fmaf(wj[t], v[t], acc[j]);
        }
    }

    bf16* op = out + (size_t)img * HW * 64 + (size_t)p0 * 64 + cog;
#pragma unroll
    for (int j = 0; j < COC; ++j)
        op[j] = __float2bfloat16(fmaxf(acc[j], 0.0f));
}

// ---------------------------------------------------------------------------
// COUT=64 conv (conv2/conv5): R10 shape — ROWS rows/block, one wave per row,
// NT=4, CHUNK=32. TPB = ROWS*64.
// ---------------------------------------------------------------------------
template<int CIN, int COUT, int NT, int ROWS, int TPB, int WPB>
__global__ __launch_bounds__(TPB, WPB) void conv_mfma_v3(const bf16* __restrict__ in,
                                                         const bf16* __restrict__ wr,
                                                         const float* __restrict__ bias,
                                                         bf16* __restrict__ out)
{
    constexpr int NCH = CIN / 32;
    __shared__ bf16 slab[(ROWS + 2) * 66 * 32];

    const int tid  = threadIdx.x;
    const int lane = tid & 63;
    const int wv   = tid >> 6;               // wave = row within tile
    const int m    = lane & 15;
    const int q    = lane >> 4;
    constexpr int YT = HH / ROWS;
    const int img  = blockIdx.y / YT;
    const int x0   = blockIdx.x * 64;
    const int y0   = (blockIdx.y % YT) * ROWS;
    const int y    = y0 + wv;

    const bf16* in_i  = in  + (size_t)img * HW * CIN;
    bf16*       out_i = out + (size_t)img * HW * COUT;

    f32x4 acc[4][NT];
#pragma unroll
    for (int f = 0; f < 4; ++f)
#pragma unroll
        for (int nt = 0; nt < NT; ++nt)
            acc[f][nt] = (f32x4){0.f, 0.f, 0.f, 0.f};

    for (int kc = 0; kc < NCH; ++kc) {
        const int k0 = kc * 32;
        __syncthreads();
        stage_slab<CIN, 32, ROWS, TPB>(in_i, slab, tid, x0, y0, k0);
        __syncthreads();

        const bf16* wbase = wr + (size_t)m * CIN + k0 + q * 8;
#pragma unroll
        for (int t = 0; t < 9; ++t) {
            const int dy = t / 3 - 1, dx = t % 3 - 1;
            const int row = wv + dy + 1;
            short8 a[4];
#pragma unroll
            for (int f = 0; f < 4; ++f) {
                const int px = f * 16 + m + dx + 1;
                const int slot = q ^ (px & 3);
                a[f] = *(const short8*)(slab + (row * 66 + px) * 32 + slot * 8);
            }
            const bf16* wt = wbase + (size_t)t * COUT * CIN;
#pragma unroll
            for (int nt = 0; nt < NT; ++nt) {
                short8 bfr = *(const short8*)(wt + (size_t)nt * 16 * CIN);
#pragma unroll
                for (int f = 0; f < 4; ++f)
                    acc[f][nt] = __builtin_amdgcn_mfma_f32_16x16x32_bf16(a[f], bfr, acc[f][nt], 0, 0, 0);
            }
        }
    }

#pragma unroll
    for (int nt = 0; nt < NT; ++nt) {
        const int co = nt * 16 + m;
        const float bb = bias[co];
#pragma unroll
        for (int f = 0; f < 4; ++f) {
#pragma unroll
            for (int r = 0; r < 4; ++r) {
                const int xp = x0 + f * 16 + q * 4 + r;
                const float v = fmaxf(acc[f][nt][r] + bb, 0.0f);
                out_i[((size_t)y * WW + xp) * COUT + co] = __float2bfloat16(v);
            }
        }
    }
}

// ---------------------------------------------------------------------------
// COUT=128 conv (conv3/conv4), retiled: 512 threads = 8 waves, TWO waves per
// pixel-row (each owns a 32-px half x all 128 couts -> 64 acc VGPRs/wave ->
// 4 waves/SIMD). CHUNK=64 K-chunks: conv3 fully resident (2 barriers total),
// conv4 2 chunks (4 barriers). Slab 50.7 KB, 2 blocks/CU.
// ---------------------------------------------------------------------------
template<int CIN>
__global__ __launch_bounds__(512, 4) void conv_mfma_c2(const bf16* __restrict__ in,
                                                       const bf16* __restrict__ wr,
                                                       const float* __restrict__ bias,
                                                       bf16* __restrict__ out)
{
    constexpr int COUT = 128, CHUNK = 64, SLOTS = 8;
    constexpr int NCH = CIN / CHUNK;
    __shared__ bf16 slab[6 * 66 * CHUNK];    // 50,688 B

    const int tid  = threadIdx.x;
    const int lane = tid & 63;
    const int wv   = tid >> 6;               // 0..7
    const int m    = lane & 15;
    const int q    = lane >> 4;
    const int r0   = wv >> 1;                // pixel-row 0..3
    const int ph   = (wv & 1) * 32;          // px-half
    const int img  = blockIdx.y >> 6;
    const int x0   = blockIdx.x * 64;
    const int y0   = (blockIdx.y & 63) * 4;
    const int y    = y0 + r0;

    const bf16* in_i  = in  + (size_t)img * HW * CIN;
    bf16*       out_i = out + (size_t)img * HW * COUT;

    f32x4 acc[2][8];
#pragma unroll
    for (int f = 0; f < 2; ++f)
#pragma unroll
        for (int nt = 0; nt < 8; ++nt)
            acc[f][nt] = (f32x4){0.f, 0.f, 0.f, 0.f};

    for (int kc = 0; kc < NCH; ++kc) {
        __syncthreads();
        stage_slab<CIN, CHUNK, 4, 512>(in_i, slab, tid, x0, y0, kc * CHUNK);
        __syncthreads();

#pragma unroll
        for (int ks = 0; ks < 2; ++ks) {     // two 32-ch sub-steps
            const int koct = ks * 4 + q;     // octet within chunk
            const bf16* wbase = wr + (size_t)m * CIN + kc * CHUNK + ks * 32 + q * 8;
#pragma unroll
            for (int t = 0; t < 9; ++t) {
                const int dy = t / 3 - 1, dx = t % 3 - 1;
                const int row = r0 + dy + 1;
                short8 a[2];
#pragma unroll
                for (int f = 0; f < 2; ++f) {
                    const int px = ph + f * 16 + m + dx + 1;
                    const int slot = koct ^ (px & (SLOTS - 1));
                    a[f] = *(const short8*)(slab + ((size_t)(row * 66 + px)) * CHUNK + slot * 8);
                }
                const bf16* wt = wbase + (size_t)t * COUT * CIN;
#pragma unroll
                for (int nt = 0; nt < 8; ++nt) {
                    short8 bfr = *(const short8*)(wt + (size_t)nt * 16 * CIN);
#pragma unroll
                    for (int f = 0; f < 2; ++f)
                        acc[f][nt] = __builtin_amdgcn_mfma_f32_16x16x32_bf16(a[f], bfr, acc[f][nt], 0, 0, 0);
                }
            }
        }
    }

    // Epilogue. C layout: col = m (=co offset), row = q*4 + r (=pixel).
#pragma unroll
    for (int nt = 0; nt < 8; ++nt) {
        const int co = nt * 16 + m;
        const float bb = bias[co];
#pragma unroll
        for (int f = 0; f < 2; ++f) {
#pragma unroll
            for (int r = 0; r < 4; ++r) {
                const int xp = x0 + ph + f * 16 + q * 4 + r;
                const float v = fmaxf(acc[f][nt][r] + bb, 0.0f);
                out_i[((size_t)y * WW + xp) * COUT + co] = __float2bfloat16(v);
            }
        }
    }
}

// ---------------------------------------------------------------------------
// Merged heads: computes BOTH kh and kv (shared staging, single slab).
// ---------------------------------------------------------------------------
__global__ __launch_bounds__(256, 2) void head_mfma2(const bf16* __restrict__ in,
                                                     const bf16* __restrict__ wrp,
                                                     const float* __restrict__ bh,
                                                     const float* __restrict__ bv,
                                                     float* __restrict__ kh_base,
                                                     float* __restrict__ kv_base,
                                                     int b0)
{
    __shared__ bf16  slab[6 * 66 * 32];     // 25,344 B
    __shared__ float smx[4][64][17];        // 17,408 B (wave-private slices)

    const int tid  = threadIdx.x;
    const int lane = tid & 63;
    const int wv   = tid >> 6;
    const int m    = lane & 15;
    const int q    = lane >> 4;
    const int img  = blockIdx.y >> 6;
    const int x0   = blockIdx.x * 64;
    const int y0   = (blockIdx.y & 63) * 4;
    const int y    = y0 + wv;

    const bf16* in_i = in + (size_t)img * HW * 64;

    f32x4 acc[4][2];
#pragma unroll
    for (int f = 0; f < 4; ++f) { acc[f][0] = (f32x4){0.f,0.f,0.f,0.f}; acc[f][1] = (f32x4){0.f,0.f,0.f,0.f}; }

    for (int kc = 0; kc < 2; ++kc) {
        const int k0 = kc * 32;
        __syncthreads();
        stage_slab<64, 32, 4, 256>(in_i, slab, tid, x0, y0, k0);
        __syncthreads();

#pragma unroll
        for (int t = 0; t < 9; ++t) {
            const int dy = t / 3 - 1, dx = t % 3 - 1;
            const int row = wv + dy + 1;
            const bf16* wt = wrp + (size_t)t * 32 * 64 + (size_t)m * 64 + k0 + q * 8;
            short8 b0f = *(const short8*)(wt);
            short8 b1f = *(const short8*)(wt + 16 * 64);
#pragma unroll
            for (int f = 0; f < 4; ++f) {
                const int px = f * 16 + m + dx + 1;
                const int slot = q ^ (px & 3);
                short8 a = *(const short8*)(slab + (row * 66 + px) * 32 + slot * 8);
                acc[f][0] = __builtin_amdgcn_mfma_f32_16x16x32_bf16(a, b0f, acc[f][0], 0, 0, 0);
                acc[f][1] = __builtin_amdgcn_mfma_f32_16x16x32_bf16(a, b1f, acc[f][1], 0, 0, 0);
            }
        }
    }

#pragma unroll
    for (int head = 0; head < 2; ++head) {
        const float* bias = head ? bv : bh;
        const float bb = (m < 11) ? bias[m] : 0.0f;
#pragma unroll
        for (int f = 0; f < 4; ++f)
#pragma unroll
            for (int r = 0; r < 4; ++r)
                smx[wv][f * 16 + q * 4 + r][m] = acc[f][head][r] + bb;

        float v[11];
#pragma unroll
        for (int j = 0; j < 11; ++j) v[j] = smx[wv][lane][j];
        float mx = v[0];
#pragma unroll
        for (int j = 1; j < 11; ++j) mx = fmaxf(mx, v[j]);
        float s = 0.0f;
#pragma unroll
        for (int j = 0; j < 11; ++j) { v[j] = expf(v[j] - mx); s += v[j]; }
        const float inv = 1.0f / s;

        float* op = (head ? kv_base : kh_base) + (size_t)(b0 + img) * 11 * HW
                    + (size_t)y * WW + x0 + lane;
#pragma unroll
        for (int j = 0; j < 11; ++j)
            op[(size_t)j * HW] = v[j] * inv;
    }
}

// ---------------------------------------------------------------------------
// Horizontal separable pass (full batch): h = sum_i kh_i * shift_x(rgb, i-5)
// ---------------------------------------------------------------------------
__global__ __launch_bounds__(256) void hpass(const float* __restrict__ rgb,
                                             const float* __restrict__ kh,
                                             float* __restrict__ h)
{
    int idx = blockIdx.x * 256 + threadIdx.x;     // b*HW + p, total 524288
    int b = idx >> 16;                            // HW = 2^16
    int p = idx & (HW - 1);
    int y = p >> 8;
    int x = p & 255;

    float kw[11];
#pragma unroll
    for (int i = 0; i < 11; ++i) kw[i] = kh[((size_t)(b * 11 + i)) * HW + p];

#pragma unroll
    for (int c = 0; c < 3; ++c) {
        const float* rp = rgb + ((size_t)(b * 3 + c)) * HW + (size_t)y * WW;
        float s = 0.0f;
#pragma unroll
        for (int i = 0; i < 11; ++i) {
            int xx = x + i - 5;
            if (xx >= 0 && xx < WW) s = fmaf(kw[i], rp[xx], s);
        }
        h[((size_t)(b * 3 + c)) * HW + p] = s;
    }
}

// ---------------------------------------------------------------------------
// Vertical pass + depth-mask composite. Writes final, blurred, mask.
// ---------------------------------------------------------------------------
__global__ __launch_bounds__(256) void vpass_compose(const float* __restrict__ h,
                                                     const float* __restrict__ kv,
                                                     const float* __restrict__ rgb,
                                                     const float* __restrict__ depth,
                                                     float* __restrict__ fin,
                                                     float* __restrict__ blur,
                                                     float* __restrict__ masko)
{
    int idx = blockIdx.x * 256 + threadIdx.x;
    int b = idx >> 16;                            // HW = 2^16
    int p = idx & (HW - 1);
    int y = p >> 8;
    int x = p & 255;

    float kw[11];
#pragma unroll
    for (int i = 0; i < 11; ++i) kw[i] = kv[((size_t)(b * 11 + i)) * HW + p];

    float d = depth[idx];
    float mk = (d > 0.2f) ? 1.0f : 0.0f;
    masko[idx] = mk;

#pragma unroll
    for (int c = 0; c < 3; ++c) {
        const float* hp = h + ((size_t)(b * 3 + c)) * HW + x;
        float s = 0.0f;
#pragma unroll
        for (int i = 0; i < 11; ++i) {
            int yy = y + i - 5;
            if (yy >= 0 && yy < HH) s = fmaf(kw[i], hp[(size_t)yy * WW], s);
        }
        size_t o = ((size_t)(b * 3 + c)) * HW + p;
        blur[o] = s;
        fin[o] = mk * rgb[o] + (1.0f - mk) * s;
    }
}

// ---------------------------------------------------------------------------
extern "C" void kernel_launch(void* const* d_in, const int* in_sizes, int n_in,
                              void* d_out, int out_size, void* d_ws, size_t ws_size,
                              hipStream_t stream)
{
    const float* rgb   = (const float*)d_in[0];
    const float* depth = (const float*)d_in[1];
    const float* w1 = (const float*)d_in[2];  const float* b1 = (const float*)d_in[3];
    const float* w2 = (const float*)d_in[4];  const float* b2 = (const float*)d_in[5];
    const float* w3 = (const float*)d_in[6];  const float* b3 = (const float*)d_in[7];
    const float* w4 = (const float*)d_in[8];  const float* b4 = (const float*)d_in[9];
    const float* w5 = (const float*)d_in[10]; const float* b5 = (const float*)d_in[11];
    const float* wh = (const float*)d_in[12]; const float* bh = (const float*)d_in[13];
    const float* wv = (const float*)d_in[14]; const float* bv = (const float*)d_in[15];

    float* out    = (float*)d_out;
    float* fin_o  = out;                    // [8,3,256,256]
    float* blur_o = out + 1572864;          // [8,3,256,256]
    float* kh_o   = out + 3145728;          // [8,11,256,256]
    float* kv_o   = out + 8912896;          // [8,11,256,256]
    float* mask_o = out + 14680064;         // [8,1,256,256]

    // --- Select batch group size G from ws_size (deterministic -> graph-safe).
    const size_t perG = (size_t)HW * 2 * (128 + 64 + 128);   // 41.9 MB per image
    const size_t wsz  = (size_t)1 * 1024 * 1024;
    int G = 1;
    if (ws_size >= 8 * perG + wsz) G = 8;
    else if (ws_size >= 4 * perG + wsz) G = 4;
    else if (ws_size >= 2 * perG + wsz) G = 2;

    char* ws = (char*)d_ws;
    const size_t szA = (size_t)G * HW * 128 * 2;
    const size_t szB = (size_t)G * HW * 64 * 2;
    const size_t szC = (size_t)G * HW * 128 * 2;
    bf16* bufA = (bf16*)ws;
    bf16* bufB = (bf16*)(ws + szA);
    bf16* bufC = (bf16*)(ws + szA + szB);
    float* hbuf = (float*)bufC;              // 6.3 MB <= szC

    bf16* w2r  = (bf16*)(ws + szA + szB + szC);
    bf16* w3r  = w2r + 9 * 64 * 64;
    bf16* w4r  = w3r + 9 * 128 * 64;
    bf16* w5r  = w4r + 9 * 128 * 128;
    bf16* whvr = w5r + 9 * 64 * 128;         // [9][32][64]

    dim3 blk(256);

    // one-time weight reorders (graph-safe: identical work every call)
    reorder_w<64, 64>  <<<dim3((9*64*64   + 255) / 256), blk, 0, stream>>>(w2, w2r);
    reorder_w<128, 64> <<<dim3((9*128*64  + 255) / 256), blk, 0, stream>>>(w3, w3r);
    reorder_w<128, 128><<<dim3((9*128*128 + 255) / 256), blk, 0, stream>>>(w4, w4r);
    reorder_w<64, 128> <<<dim3((9*64*128  + 255) / 256), blk, 0, stream>>>(w5, w5r);
    reorder_w_head2    <<<dim3((9*32*64   + 255) / 256), blk, 0, stream>>>(wh, wv, whvr);

    for (int b0 = 0; b0 < BB; b0 += G) {
        conv3x3_first<16><<<dim3(4, 64 * G, 4), blk, 0, stream>>>(rgb, depth, w1, b1, bufA, b0);
        // COUT=64 layers: 8-row 512-thread blocks (R10 shape)
        conv_mfma_v3<64, 64, 4, 8, 512, 4> <<<dim3(4, 32 * G), dim3(512), 0, stream>>>(bufA, w2r, b2, bufB);
        // COUT=128 layers: 512-thread 2-waves-per-row, CHUNK=64
        conv_mfma_c2<64>  <<<dim3(4, 64 * G), dim3(512), 0, stream>>>(bufB, w3r, b3, bufC);
        conv_mfma_c2<128> <<<dim3(4, 64 * G), dim3(512), 0, stream>>>(bufC, w4r, b4, bufA);
        conv_mfma_v3<128, 64, 4, 8, 512, 4><<<dim3(4, 32 * G), dim3(512), 0, stream>>>(bufA, w5r, b5, bufB);
        head_mfma2<<<dim3(4, 64 * G), blk, 0, stream>>>(bufB, whvr, bh, bv, kh_o, kv_o, b0);
    }

    // separable blur + composite (full batch; bufC/f3 dead by now)
    hpass<<<dim3(2048), blk, 0, stream>>>(rgb, kh_o, hbuf);
    vpass_compose<<<dim3(2048), blk, 0, stream>>>(hbuf, kv_o, rgb, depth,
                                                  fin_o, blur_o, mask_o);
}

// Round 12
// 1338.139 us; speedup vs baseline: 1.2378x; 1.2378x over previous
//
#include <hip/hip_runtime.h>
#include <hip/hip_bf16.h>
#include <math.h>

// Problem constants (B=8, H=W=256, K=11 taps, thresh 0.2)
#define HH 256
#define WW 256
#define HW (HH*WW)
#define BB 8

typedef __hip_bfloat16 bf16;
typedef __attribute__((ext_vector_type(8))) short short8;   // 8 bf16 (4 VGPRs)
typedef __attribute__((ext_vector_type(4))) float f32x4;    // MFMA acc

// Slab: [(ROWS+2) rows][66 px][CHUNK ch] bf16. XOR swizzle with
// SLOTS = CHUNK/8 16B-slots per pixel: slot s holds channel-octet
// seg = s ^ (px & (SLOTS-1)). Staging writes are unit-linear (contiguous),
// b128 A-reads use slot = koct ^ (px&(SLOTS-1)); both hit each bank the
// conflict-free minimum 8x per wave64 access.

// ---------------------------------------------------------------------------
// Weight reorder: OIHW f32 -> [t][co][ci] bf16 (t = ky*3+kx)
// ---------------------------------------------------------------------------
template<int CO, int CI>
__global__ __launch_bounds__(256) void reorder_w(const float* __restrict__ w,
                                                 bf16* __restrict__ wr)
{
    int idx = blockIdx.x * 256 + threadIdx.x;
    if (idx >= 9 * CO * CI) return;
    int ci = idx % CI;
    int co = (idx / CI) % CO;
    int t  = idx / (CI * CO);
    wr[idx] = __float2bfloat16(w[((size_t)co * CI + ci) * 9 + t]);
}

// Both head weights -> one [9][32][64] bf16 buffer: co 0..10 = wh, 16..26 = wv.
__global__ __launch_bounds__(256) void reorder_w_head2(const float* __restrict__ wh,
                                                       const float* __restrict__ wv,
                                                       bf16* __restrict__ wr)
{
    int idx = blockIdx.x * 256 + threadIdx.x;
    if (idx >= 9 * 32 * 64) return;
    int ci = idx % 64;
    int co = (idx / 64) % 32;
    int t  = idx / (64 * 32);
    const float* src = (co < 16) ? wh : wv;
    int c = co & 15;
    float v = (c < 11) ? src[((size_t)c * 64 + ci) * 9 + t] : 0.0f;
    wr[idx] = __float2bfloat16(v);
}

// ---------------------------------------------------------------------------
// Vector-load staging of one CHUNK-ch chunk into the XOR-swizzled slab.
// OOB lanes write zero.
// ---------------------------------------------------------------------------
template<int CIN, int CHUNK, int ROWS, int TPB>
__device__ __forceinline__ void stage_slab(const bf16* __restrict__ in_i,
                                           bf16* __restrict__ slab,
                                           int tid, int x0, int y0, int k0)
{
    constexpr int SLOTS = CHUNK / 8;
    constexpr int UNITS = (ROWS + 2) * 66 * SLOTS;
    const short8 z8 = {0,0,0,0,0,0,0,0};
    for (int e = tid; e < UNITS; e += TPB) {
        int row = e / (66 * SLOTS), rem = e - row * (66 * SLOTS);
        int px = rem / SLOTS, slot = rem % SLOTS;
        int seg = slot ^ (px & (SLOTS - 1));
        int yy = y0 - 1 + row, xx = x0 - 1 + px;
        short8 v = z8;
        if (yy >= 0 && yy < HH && xx >= 0 && xx < WW)
            v = *(const short8*)(in_i + ((size_t)(yy * WW + xx)) * CIN + k0 + seg * 8);
        *(short8*)(slab + (size_t)e * 8) = v;
    }
}

// ---------------------------------------------------------------------------
// conv1: 3x3 conv over concat(rgb,depth) [4ch f32 planar], ReLU,
// output NHWC bf16 [G][HW][64]. blockIdx.y = img*64 + ytile.
// ---------------------------------------------------------------------------
template<int COC>
__global__ __launch_bounds__(256) void conv3x3_first(const float* __restrict__ rgb,
                                                     const float* __restrict__ depth,
                                                     const float* __restrict__ w,
                                                     const float* __restrict__ bias,
                                                     bf16* __restrict__ out, int b0)
{
    const int tid = threadIdx.x;
    const int img = blockIdx.y >> 6;
    const int b   = b0 + img;
    const int x = blockIdx.x * 64 + (tid & 63);
    const int y = (blockIdx.y & 63) * 4 + (tid >> 6);
    const int cog = blockIdx.z * COC;

    const bool vy0 = (y > 0), vy2 = (y < HH - 1);
    const bool vx0 = (x > 0), vx2 = (x < WW - 1);
    bool val[9];
    int  off[9];
    {
        int t = 0;
        for (int dy = -1; dy <= 1; ++dy)
            for (int dx = -1; dx <= 1; ++dx) {
                val[t] = (dy < 0 ? vy0 : (dy > 0 ? vy2 : true)) &&
                         (dx < 0 ? vx0 : (dx > 0 ? vx2 : true));
                off[t] = dy * WW + dx;
                ++t;
            }
    }

    float acc[COC];
#pragma unroll
    for (int j = 0; j < COC; ++j) acc[j] = bias[cog + j];

    const int p0 = y * WW + x;
#pragma unroll
    for (int ci = 0; ci < 4; ++ci) {
        const float* p = (ci < 3) ? (rgb + ((size_t)(b * 3 + ci)) * HW + p0)
                                  : (depth + (size_t)b * HW + p0);
        float v[9];
#pragma unroll
        for (int t = 0; t < 9; ++t)
            v[t] = val[t] ? p[off[t]] : 0.0f;

        const float* wp = w + ((size_t)cog * 4 + ci) * 9;
#pragma unroll
        for (int j = 0; j < COC; ++j) {
            const float* wj = wp + (size_t)j * 4 * 9;
#pragma unroll
            for (int t = 0; t < 9; ++t)
                acc[j] = fmaf(wj[t], v[t], acc[j]);
        }
    }

    bf16* op = out + (size_t)img * HW * 64 + (size_t)p0 * 64 + cog;
#pragma unroll
    for (int j = 0; j < COC; ++j)
        op[j] = __float2bfloat16(fmaxf(acc[j], 0.0f));
}

// ---------------------------------------------------------------------------
// MFMA implicit-GEMM 3x3 conv: ROWS rows/block, ONE wave per row (R10 wave
// tile, compiler-verified no-spill), CHUNK-channel K-chunks.
// in : NHWC bf16 [G][HW][CIN]   wr : bf16 [9][COUT][CIN]   out : [G][HW][COUT]
// ---------------------------------------------------------------------------
template<int CIN, int COUT, int NT, int ROWS, int TPB, int WPB, int CHUNK>
__global__ __launch_bounds__(TPB, WPB) void conv_mfma_v4(const bf16* __restrict__ in,
                                                         const bf16* __restrict__ wr,
                                                         const float* __restrict__ bias,
                                                         bf16* __restrict__ out)
{
    constexpr int SLOTS = CHUNK / 8;
    constexpr int NCH = CIN / CHUNK;
    constexpr int NKS = CHUNK / 32;
    __shared__ bf16 slab[(ROWS + 2) * 66 * CHUNK];

    const int tid  = threadIdx.x;
    const int lane = tid & 63;
    const int wv   = tid >> 6;               // wave = row within tile
    const int m    = lane & 15;
    const int q    = lane >> 4;
    constexpr int YT = HH / ROWS;
    const int img  = blockIdx.y / YT;
    const int x0   = blockIdx.x * 64;
    const int y0   = (blockIdx.y % YT) * ROWS;
    const int y    = y0 + wv;

    const bf16* in_i  = in  + (size_t)img * HW * CIN;
    bf16*       out_i = out + (size_t)img * HW * COUT;

    f32x4 acc[4][NT];
#pragma unroll
    for (int f = 0; f < 4; ++f)
#pragma unroll
        for (int nt = 0; nt < NT; ++nt)
            acc[f][nt] = (f32x4){0.f, 0.f, 0.f, 0.f};

    for (int kc = 0; kc < NCH; ++kc) {
        __syncthreads();
        stage_slab<CIN, CHUNK, ROWS, TPB>(in_i, slab, tid, x0, y0, kc * CHUNK);
        __syncthreads();

#pragma unroll
        for (int ks = 0; ks < NKS; ++ks) {
            const int koct = ks * 4 + q;
            const bf16* wbase = wr + (size_t)m * CIN + kc * CHUNK + ks * 32 + q * 8;
#pragma unroll
            for (int t = 0; t < 9; ++t) {
                const int dy = t / 3 - 1, dx = t % 3 - 1;
                const int row = wv + dy + 1;
                short8 a[4];
#pragma unroll
                for (int f = 0; f < 4; ++f) {
                    const int px = f * 16 + m + dx + 1;
                    const int slot = koct ^ (px & (SLOTS - 1));
                    a[f] = *(const short8*)(slab + ((size_t)(row * 66 + px)) * CHUNK + slot * 8);
                }
                const bf16* wt = wbase + (size_t)t * COUT * CIN;
#pragma unroll
                for (int nt = 0; nt < NT; ++nt) {
                    short8 bfr = *(const short8*)(wt + (size_t)nt * 16 * CIN);
#pragma unroll
                    for (int f = 0; f < 4; ++f)
                        acc[f][nt] = __builtin_amdgcn_mfma_f32_16x16x32_bf16(a[f], bfr, acc[f][nt], 0, 0, 0);
                }
            }
        }
    }

    // Epilogue. C/D layout: col = lane&15 (=co offset), row = q*4 + reg (=pixel).
#pragma unroll
    for (int nt = 0; nt < NT; ++nt) {
        const int co = nt * 16 + m;
        const float bb = bias[co];
#pragma unroll
        for (int f = 0; f < 4; ++f) {
#pragma unroll
            for (int r = 0; r < 4; ++r) {
                const int xp = x0 + f * 16 + q * 4 + r;
                const float v = fmaxf(acc[f][nt][r] + bb, 0.0f);
                out_i[((size_t)y * WW + xp) * COUT + co] = __float2bfloat16(v);
            }
        }
    }
}

// ---------------------------------------------------------------------------
// Merged heads: computes BOTH kh and kv (shared staging, single slab).
// ---------------------------------------------------------------------------
__global__ __launch_bounds__(256, 2) void head_mfma2(const bf16* __restrict__ in,
                                                     const bf16* __restrict__ wrp,
                                                     const float* __restrict__ bh,
                                                     const float* __restrict__ bv,
                                                     float* __restrict__ kh_base,
                                                     float* __restrict__ kv_base,
                                                     int b0)
{
    __shared__ bf16  slab[6 * 66 * 32];     // 25,344 B
    __shared__ float smx[4][64][17];        // 17,408 B (wave-private slices)

    const int tid  = threadIdx.x;
    const int lane = tid & 63;
    const int wv   = tid >> 6;
    const int m    = lane & 15;
    const int q    = lane >> 4;
    const int img  = blockIdx.y >> 6;
    const int x0   = blockIdx.x * 64;
    const int y0   = (blockIdx.y & 63) * 4;
    const int y    = y0 + wv;

    const bf16* in_i = in + (size_t)img * HW * 64;

    f32x4 acc[4][2];
#pragma unroll
    for (int f = 0; f < 4; ++f) { acc[f][0] = (f32x4){0.f,0.f,0.f,0.f}; acc[f][1] = (f32x4){0.f,0.f,0.f,0.f}; }

    for (int kc = 0; kc < 2; ++kc) {
        const int k0 = kc * 32;
        __syncthreads();
        stage_slab<64, 32, 4, 256>(in_i, slab, tid, x0, y0, k0);
        __syncthreads();

#pragma unroll
        for (int t = 0; t < 9; ++t) {
            const int dy = t / 3 - 1, dx = t % 3 - 1;
            const int row = wv + dy + 1;
            const bf16* wt = wrp + (size_t)t * 32 * 64 + (size_t)m * 64 + k0 + q * 8;
            short8 b0f = *(const short8*)(wt);
            short8 b1f = *(const short8*)(wt + 16 * 64);
#pragma unroll
            for (int f = 0; f < 4; ++f) {
                const int px = f * 16 + m + dx + 1;
                const int slot = q ^ (px & 3);
                short8 a = *(const short8*)(slab + (row * 66 + px) * 32 + slot * 8);
                acc[f][0] = __builtin_amdgcn_mfma_f32_16x16x32_bf16(a, b0f, acc[f][0], 0, 0, 0);
                acc[f][1] = __builtin_amdgcn_mfma_f32_16x16x32_bf16(a, b1f, acc[f][1], 0, 0, 0);
            }
        }
    }

#pragma unroll
    for (int head = 0; head < 2; ++head) {
        const float* bias = head ? bv : bh;
        const float bb = (m < 11) ? bias[m] : 0.0f;
#pragma unroll
        for (int f = 0; f < 4; ++f)
#pragma unroll
            for (int r = 0; r < 4; ++r)
                smx[wv][f * 16 + q * 4 + r][m] = acc[f][head][r] + bb;

        float v[11];
#pragma unroll
        for (int j = 0; j < 11; ++j) v[j] = smx[wv][lane][j];
        float mx = v[0];
#pragma unroll
        for (int j = 1; j < 11; ++j) mx = fmaxf(mx, v[j]);
        float s = 0.0f;
#pragma unroll
        for (int j = 0; j < 11; ++j) { v[j] = expf(v[j] - mx); s += v[j]; }
        const float inv = 1.0f / s;

        float* op = (head ? kv_base : kh_base) + (size_t)(b0 + img) * 11 * HW
                    + (size_t)y * WW + x0 + lane;
#pragma unroll
        for (int j = 0; j < 11; ++j)
            op[(size_t)j * HW] = v[j] * inv;
    }
}

// ---------------------------------------------------------------------------
// Horizontal separable pass (full batch): h = sum_i kh_i * shift_x(rgb, i-5)
// ---------------------------------------------------------------------------
__global__ __launch_bounds__(256) void hpass(const float* __restrict__ rgb,
                                             const float* __restrict__ kh,
                                             float* __restrict__ h)
{
    int idx = blockIdx.x * 256 + threadIdx.x;     // b*HW + p, total 524288
    int b = idx >> 16;                            // HW = 2^16
    int p = idx & (HW - 1);
    int y = p >> 8;
    int x = p & 255;

    float kw[11];
#pragma unroll
    for (int i = 0; i < 11; ++i) kw[i] = kh[((size_t)(b * 11 + i)) * HW + p];

#pragma unroll
    for (int c = 0; c < 3; ++c) {
        const float* rp = rgb + ((size_t)(b * 3 + c)) * HW + (size_t)y * WW;
        float s = 0.0f;
#pragma unroll
        for (int i = 0; i < 11; ++i) {
            int xx = x + i - 5;
            if (xx >= 0 && xx < WW) s = fmaf(kw[i], rp[xx], s);
        }
        h[((size_t)(b * 3 + c)) * HW + p] = s;
    }
}

// ---------------------------------------------------------------------------
// Vertical pass + depth-mask composite. Writes final, blurred, mask.
// ---------------------------------------------------------------------------
__global__ __launch_bounds__(256) void vpass_compose(const float* __restrict__ h,
                                                     const float* __restrict__ kv,
                                                     const float* __restrict__ rgb,
                                                     const float* __restrict__ depth,
                                                     float* __restrict__ fin,
                                                     float* __restrict__ blur,
                                                     float* __restrict__ masko)
{
    int idx = blockIdx.x * 256 + threadIdx.x;
    int b = idx >> 16;                            // HW = 2^16
    int p = idx & (HW - 1);
    int y = p >> 8;
    int x = p & 255;

    float kw[11];
#pragma unroll
    for (int i = 0; i < 11; ++i) kw[i] = kv[((size_t)(b * 11 + i)) * HW + p];

    float d = depth[idx];
    float mk = (d > 0.2f) ? 1.0f : 0.0f;
    masko[idx] = mk;

#pragma unroll
    for (int c = 0; c < 3; ++c) {
        const float* hp = h + ((size_t)(b * 3 + c)) * HW + x;
        float s = 0.0f;
#pragma unroll
        for (int i = 0; i < 11; ++i) {
            int yy = y + i - 5;
            if (yy >= 0 && yy < HH) s = fmaf(kw[i], hp[(size_t)yy * WW], s);
        }
        size_t o = ((size_t)(b * 3 + c)) * HW + p;
        blur[o] = s;
        fin[o] = mk * rgb[o] + (1.0f - mk) * s;
    }
}

// ---------------------------------------------------------------------------
extern "C" void kernel_launch(void* const* d_in, const int* in_sizes, int n_in,
                              void* d_out, int out_size, void* d_ws, size_t ws_size,
                              hipStream_t stream)
{
    const float* rgb   = (const float*)d_in[0];
    const float* depth = (const float*)d_in[1];
    const float* w1 = (const float*)d_in[2];  const float* b1 = (const float*)d_in[3];
    const float* w2 = (const float*)d_in[4];  const float* b2 = (const float*)d_in[5];
    const float* w3 = (const float*)d_in[6];  const float* b3 = (const float*)d_in[7];
    const float* w4 = (const float*)d_in[8];  const float* b4 = (const float*)d_in[9];
    const float* w5 = (const float*)d_in[10]; const float* b5 = (const float*)d_in[11];
    const float* wh = (const float*)d_in[12]; const float* bh = (const float*)d_in[13];
    const float* wv = (const float*)d_in[14]; const float* bv = (const float*)d_in[15];

    float* out    = (float*)d_out;
    float* fin_o  = out;                    // [8,3,256,256]
    float* blur_o = out + 1572864;          // [8,3,256,256]
    float* kh_o   = out + 3145728;          // [8,11,256,256]
    float* kv_o   = out + 8912896;          // [8,11,256,256]
    float* mask_o = out + 14680064;         // [8,1,256,256]

    // --- Select batch group size G from ws_size (deterministic -> graph-safe).
    const size_t perG = (size_t)HW * 2 * (128 + 64 + 128);   // 41.9 MB per image
    const size_t wsz  = (size_t)1 * 1024 * 1024;
    int G = 1;
    if (ws_size >= 8 * perG + wsz) G = 8;
    else if (ws_size >= 4 * perG + wsz) G = 4;
    else if (ws_size >= 2 * perG + wsz) G = 2;

    char* ws = (char*)d_ws;
    const size_t szA = (size_t)G * HW * 128 * 2;
    const size_t szB = (size_t)G * HW * 64 * 2;
    const size_t szC = (size_t)G * HW * 128 * 2;
    bf16* bufA = (bf16*)ws;
    bf16* bufB = (bf16*)(ws + szA);
    bf16* bufC = (bf16*)(ws + szA + szB);
    float* hbuf = (float*)bufC;              // 6.3 MB <= szC

    bf16* w2r  = (bf16*)(ws + szA + szB + szC);
    bf16* w3r  = w2r + 9 * 64 * 64;
    bf16* w4r  = w3r + 9 * 128 * 64;
    bf16* w5r  = w4r + 9 * 128 * 128;
    bf16* whvr = w5r + 9 * 64 * 128;         // [9][32][64]

    dim3 blk(256);

    // one-time weight reorders (graph-safe: identical work every call)
    reorder_w<64, 64>  <<<dim3((9*64*64   + 255) / 256), blk, 0, stream>>>(w2, w2r);
    reorder_w<128, 64> <<<dim3((9*128*64  + 255) / 256), blk, 0, stream>>>(w3, w3r);
    reorder_w<128, 128><<<dim3((9*128*128 + 255) / 256), blk, 0, stream>>>(w4, w4r);
    reorder_w<64, 128> <<<dim3((9*64*128  + 255) / 256), blk, 0, stream>>>(w5, w5r);
    reorder_w_head2    <<<dim3((9*32*64   + 255) / 256), blk, 0, stream>>>(wh, wv, whvr);

    for (int b0 = 0; b0 < BB; b0 += G) {
        conv3x3_first<16><<<dim3(4, 64 * G, 4), blk, 0, stream>>>(rgb, depth, w1, b1, bufA, b0);
        // conv2/conv5 (COUT=64): R10 shape — 8 rows, 512 thr, NT=4, CHUNK=32
        conv_mfma_v4<64, 64, 4, 8, 512, 4, 32> <<<dim3(4, 32 * G), dim3(512), 0, stream>>>(bufA, w2r, b2, bufB);
        // conv3/conv4 (COUT=128): R10 wave tile (4 rows, 256 thr, NT=8) + CHUNK=64
        conv_mfma_v4<64, 128, 8, 4, 256, 2, 64><<<dim3(4, 64 * G), blk, 0, stream>>>(bufB, w3r, b3, bufC);
        conv_mfma_v4<128,128, 8, 4, 256, 2, 64><<<dim3(4, 64 * G), blk, 0, stream>>>(bufC, w4r, b4, bufA);
        conv_mfma_v4<128, 64, 4, 8, 512, 4, 32><<<dim3(4, 32 * G), dim3(512), 0, stream>>>(bufA, w5r, b5, bufB);
        head_mfma2<<<dim3(4, 64 * G), blk, 0, stream>>>(bufB, whvr, bh, bv, kh_o, kv_o, b0);
    }

    // separable blur + composite (full batch; bufC/f3 dead by now)
    hpass<<<dim3(2048), blk, 0, stream>>>(rgb, kh_o, hbuf);
    vpass_compose<<<dim3(2048), blk, 0, stream>>>(hbuf, kv_o, rgb, depth,
                                                  fin_o, blur_o, mask_o);
}

// Round 13
// 1179.448 us; speedup vs baseline: 1.4043x; 1.1345x over previous
//
#include <hip/hip_runtime.h>
#include <hip/hip_bf16.h>
#include <math.h>

// Problem constants (B=8, H=W=256, K=11 taps, thresh 0.2)
#define HH 256
#define WW 256
#define HW (HH*WW)
#define BB 8

typedef __hip_bfloat16 bf16;
typedef __attribute__((ext_vector_type(8))) short short8;   // 8 bf16 (4 VGPRs)
typedef __attribute__((ext_vector_type(4))) float f32x4;    // MFMA acc

// Slab: [(ROWS+2) rows][66 px][32 ch] bf16. XOR swizzle: LDS slot s of pixel
// px holds channel-octet seg = s ^ (px&3) -> staging writes (unit-linear) and
// b128 A-reads (slot = q ^ (px&3)) both hit each bank the conflict-free
// minimum 8x per wave64 access.

// ---------------------------------------------------------------------------
// All weight reorders in ONE launch. Layout (bf16, contiguous from base):
//   [0)        w2r  9*64*64    OIHW(64,64)   -> [t][co][ci]
//   [36864)    w3r  9*128*64   OIHW(128,64)
//   [110592)   w4r  9*128*128  OIHW(128,128)
//   [258048)   w5r  9*64*128   OIHW(64,128)
//   [331776)   whvr 9*32*64    co 0..10 = wh, 16..26 = wv, rest 0
//   total 350208 elements
// ---------------------------------------------------------------------------
__global__ __launch_bounds__(256) void reorder_all(const float* __restrict__ w2,
                                                   const float* __restrict__ w3,
                                                   const float* __restrict__ w4,
                                                   const float* __restrict__ w5,
                                                   const float* __restrict__ wh,
                                                   const float* __restrict__ wv,
                                                   bf16* __restrict__ base)
{
    int idx = blockIdx.x * 256 + threadIdx.x;
    if (idx >= 350208) return;
    float v;
    if (idx < 36864) {
        int e = idx, ci = e % 64, co = (e / 64) % 64, t = e / (64 * 64);
        v = w2[((size_t)co * 64 + ci) * 9 + t];
    } else if (idx < 110592) {
        int e = idx - 36864, ci = e % 64, co = (e / 64) % 128, t = e / (64 * 128);
        v = w3[((size_t)co * 64 + ci) * 9 + t];
    } else if (idx < 258048) {
        int e = idx - 110592, ci = e % 128, co = (e / 128) % 128, t = e / (128 * 128);
        v = w4[((size_t)co * 128 + ci) * 9 + t];
    } else if (idx < 331776) {
        int e = idx - 258048, ci = e % 128, co = (e / 128) % 64, t = e / (128 * 64);
        v = w5[((size_t)co * 128 + ci) * 9 + t];
    } else {
        int e = idx - 331776, ci = e % 64, co = (e / 64) % 32, t = e / (64 * 32);
        const float* src = (co < 16) ? wh : wv;
        int c = co & 15;
        v = (c < 11) ? src[((size_t)c * 64 + ci) * 9 + t] : 0.0f;
    }
    base[idx] = __float2bfloat16(v);
}

// ---------------------------------------------------------------------------
// Vector-load staging of one 32-ch chunk into the XOR-swizzled slab.
// OOB lanes write zero.
// ---------------------------------------------------------------------------
template<int CIN, int ROWS, int TPB>
__device__ __forceinline__ void stage_slab(const bf16* __restrict__ in_i,
                                           bf16* __restrict__ slab,
                                           int tid, int x0, int y0, int k0)
{
    constexpr int UNITS = (ROWS + 2) * 264;      // 16B units
    const short8 z8 = {0,0,0,0,0,0,0,0};
    for (int e = tid; e < UNITS; e += TPB) {
        int row = e / 264, rem = e - row * 264;
        int px = rem >> 2, slot = rem & 3;
        int seg = slot ^ (px & 3);
        int yy = y0 - 1 + row, xx = x0 - 1 + px;
        short8 v = z8;
        if (yy >= 0 && yy < HH && xx >= 0 && xx < WW)
            v = *(const short8*)(in_i + ((size_t)(yy * WW + xx)) * CIN + k0 + seg * 8);
        *(short8*)(slab + (size_t)e * 8) = v;
    }
}

// ---------------------------------------------------------------------------
// conv1: 3x3 conv over concat(rgb,depth) [4ch f32 planar], ReLU,
// output NHWC bf16 [G][HW][64]. COC=64: ONE z-slice -> each input tap loaded
// once (was 4x with COC=16). Proven loop structure (outer ci, inner j,t).
// ---------------------------------------------------------------------------
__global__ __launch_bounds__(256) void conv3x3_first64(const float* __restrict__ rgb,
                                                       const float* __restrict__ depth,
                                                       const float* __restrict__ w,
                                                       const float* __restrict__ bias,
                                                       bf16* __restrict__ out, int b0)
{
    const int tid = threadIdx.x;
    const int img = blockIdx.y >> 6;
    const int b   = b0 + img;
    const int x = blockIdx.x * 64 + (tid & 63);
    const int y = (blockIdx.y & 63) * 4 + (tid >> 6);

    const bool vy0 = (y > 0), vy2 = (y < HH - 1);
    const bool vx0 = (x > 0), vx2 = (x < WW - 1);
    bool val[9];
    int  off[9];
    {
        int t = 0;
        for (int dy = -1; dy <= 1; ++dy)
            for (int dx = -1; dx <= 1; ++dx) {
                val[t] = (dy < 0 ? vy0 : (dy > 0 ? vy2 : true)) &&
                         (dx < 0 ? vx0 : (dx > 0 ? vx2 : true));
                off[t] = dy * WW + dx;
                ++t;
            }
    }

    float acc[64];
#pragma unroll
    for (int j = 0; j < 64; ++j) acc[j] = bias[j];

    const int p0 = y * WW + x;
#pragma unroll
    for (int ci = 0; ci < 4; ++ci) {
        const float* p = (ci < 3) ? (rgb + ((size_t)(b * 3 + ci)) * HW + p0)
                                  : (depth + (size_t)b * HW + p0);
        float v[9];
#pragma unroll
        for (int t = 0; t < 9; ++t)
            v[t] = val[t] ? p[off[t]] : 0.0f;

        const float* wp = w + (size_t)ci * 9;
#pragma unroll
        for (int j = 0; j < 64; ++j) {
            const float* wj = wp + (size_t)j * 4 * 9;
#pragma unroll
            for (int t = 0; t < 9; ++t)
                acc[j] = fmaf(wj[t], v[t], acc[j]);
        }
    }

    bf16* op = out + (size_t)img * HW * 64 + (size_t)p0 * 64;
#pragma unroll
    for (int j = 0; j < 64; ++j)
        op[j] = __float2bfloat16(fmaxf(acc[j], 0.0f));
}

// ---------------------------------------------------------------------------
// MFMA implicit-GEMM 3x3 conv (R10 proven shapes): ROWS rows/block, one wave
// per row, NT co-tiles, CHUNK=32.
// in : NHWC bf16 [G][HW][CIN]   wr : bf16 [9][COUT][CIN]   out : [G][HW][COUT]
// ---------------------------------------------------------------------------
template<int CIN, int COUT, int NT, int ROWS, int TPB, int WPB>
__global__ __launch_bounds__(TPB, WPB) void conv_mfma_v3(const bf16* __restrict__ in,
                                                         const bf16* __restrict__ wr,
                                                         const float* __restrict__ bias,
                                                         bf16* __restrict__ out)
{
    constexpr int NCH = CIN / 32;
    __shared__ bf16 slab[(ROWS + 2) * 66 * 32];

    const int tid  = threadIdx.x;
    const int lane = tid & 63;
    const int wv   = tid >> 6;               // wave = row within tile
    const int m    = lane & 15;
    const int q    = lane >> 4;
    constexpr int YT = HH / ROWS;
    const int img  = blockIdx.y / YT;
    const int x0   = blockIdx.x * 64;
    const int y0   = (blockIdx.y % YT) * ROWS;
    const int y    = y0 + wv;

    const bf16* in_i  = in  + (size_t)img * HW * CIN;
    bf16*       out_i = out + (size_t)img * HW * COUT;

    f32x4 acc[4][NT];
#pragma unroll
    for (int f = 0; f < 4; ++f)
#pragma unroll
        for (int nt = 0; nt < NT; ++nt)
            acc[f][nt] = (f32x4){0.f, 0.f, 0.f, 0.f};

    for (int kc = 0; kc < NCH; ++kc) {
        const int k0 = kc * 32;
        __syncthreads();
        stage_slab<CIN, ROWS, TPB>(in_i, slab, tid, x0, y0, k0);
        __syncthreads();

        const bf16* wbase = wr + (size_t)m * CIN + k0 + q * 8;
#pragma unroll
        for (int t = 0; t < 9; ++t) {
            const int dy = t / 3 - 1, dx = t % 3 - 1;
            const int row = wv + dy + 1;
            short8 a[4];
#pragma unroll
            for (int f = 0; f < 4; ++f) {
                const int px = f * 16 + m + dx + 1;
                const int slot = q ^ (px & 3);
                a[f] = *(const short8*)(slab + (row * 66 + px) * 32 + slot * 8);
            }
            const bf16* wt = wbase + (size_t)t * COUT * CIN;
#pragma unroll
            for (int nt = 0; nt < NT; ++nt) {
                short8 bfr = *(const short8*)(wt + (size_t)nt * 16 * CIN);
#pragma unroll
                for (int f = 0; f < 4; ++f)
                    acc[f][nt] = __builtin_amdgcn_mfma_f32_16x16x32_bf16(a[f], bfr, acc[f][nt], 0, 0, 0);
            }
        }
    }

    // Epilogue. C/D layout: col = lane&15 (=co offset), row = q*4 + reg (=pixel).
#pragma unroll
    for (int nt = 0; nt < NT; ++nt) {
        const int co = nt * 16 + m;
        const float bb = bias[co];
#pragma unroll
        for (int f = 0; f < 4; ++f) {
#pragma unroll
            for (int r = 0; r < 4; ++r) {
                const int xp = x0 + f * 16 + q * 4 + r;
                const float v = fmaxf(acc[f][nt][r] + bb, 0.0f);
                out_i[((size_t)y * WW + xp) * COUT + co] = __float2bfloat16(v);
            }
        }
    }
}

// ---------------------------------------------------------------------------
// Merged heads: computes BOTH kh and kv (shared staging, single slab).
// ---------------------------------------------------------------------------
__global__ __launch_bounds__(256, 2) void head_mfma2(const bf16* __restrict__ in,
                                                     const bf16* __restrict__ wrp,
                                                     const float* __restrict__ bh,
                                                     const float* __restrict__ bv,
                                                     float* __restrict__ kh_base,
                                                     float* __restrict__ kv_base,
                                                     int b0)
{
    __shared__ bf16  slab[6 * 66 * 32];     // 25,344 B
    __shared__ float smx[4][64][17];        // 17,408 B (wave-private slices)

    const int tid  = threadIdx.x;
    const int lane = tid & 63;
    const int wv   = tid >> 6;
    const int m    = lane & 15;
    const int q    = lane >> 4;
    const int img  = blockIdx.y >> 6;
    const int x0   = blockIdx.x * 64;
    const int y0   = (blockIdx.y & 63) * 4;
    const int y    = y0 + wv;

    const bf16* in_i = in + (size_t)img * HW * 64;

    f32x4 acc[4][2];
#pragma unroll
    for (int f = 0; f < 4; ++f) { acc[f][0] = (f32x4){0.f,0.f,0.f,0.f}; acc[f][1] = (f32x4){0.f,0.f,0.f,0.f}; }

    for (int kc = 0; kc < 2; ++kc) {
        const int k0 = kc * 32;
        __syncthreads();
        stage_slab<64, 4, 256>(in_i, slab, tid, x0, y0, k0);
        __syncthreads();

#pragma unroll
        for (int t = 0; t < 9; ++t) {
            const int dy = t / 3 - 1, dx = t % 3 - 1;
            const int row = wv + dy + 1;
            const bf16* wt = wrp + (size_t)t * 32 * 64 + (size_t)m * 64 + k0 + q * 8;
            short8 b0f = *(const short8*)(wt);
            short8 b1f = *(const short8*)(wt + 16 * 64);
#pragma unroll
            for (int f = 0; f < 4; ++f) {
                const int px = f * 16 + m + dx + 1;
                const int slot = q ^ (px & 3);
                short8 a = *(const short8*)(slab + (row * 66 + px) * 32 + slot * 8);
                acc[f][0] = __builtin_amdgcn_mfma_f32_16x16x32_bf16(a, b0f, acc[f][0], 0, 0, 0);
                acc[f][1] = __builtin_amdgcn_mfma_f32_16x16x32_bf16(a, b1f, acc[f][1], 0, 0, 0);
            }
        }
    }

#pragma unroll
    for (int head = 0; head < 2; ++head) {
        const float* bias = head ? bv : bh;
        const float bb = (m < 11) ? bias[m] : 0.0f;
#pragma unroll
        for (int f = 0; f < 4; ++f)
#pragma unroll
            for (int r = 0; r < 4; ++r)
                smx[wv][f * 16 + q * 4 + r][m] = acc[f][head][r] + bb;

        float v[11];
#pragma unroll
        for (int j = 0; j < 11; ++j) v[j] = smx[wv][lane][j];
        float mx = v[0];
#pragma unroll
        for (int j = 1; j < 11; ++j) mx = fmaxf(mx, v[j]);
        float s = 0.0f;
#pragma unroll
        for (int j = 0; j < 11; ++j) { v[j] = expf(v[j] - mx); s += v[j]; }
        const float inv = 1.0f / s;

        float* op = (head ? kv_base : kh_base) + (size_t)(b0 + img) * 11 * HW
                    + (size_t)y * WW + x0 + lane;
#pragma unroll
        for (int j = 0; j < 11; ++j)
            op[(size_t)j * HW] = v[j] * inv;
    }
}

// ---------------------------------------------------------------------------
// Horizontal separable pass (full batch): h = sum_i kh_i * shift_x(rgb, i-5)
// ---------------------------------------------------------------------------
__global__ __launch_bounds__(256) void hpass(const float* __restrict__ rgb,
                                             const float* __restrict__ kh,
                                             float* __restrict__ h)
{
    int idx = blockIdx.x * 256 + threadIdx.x;     // b*HW + p, total 524288
    int b = idx >> 16;                            // HW = 2^16
    int p = idx & (HW - 1);
    int y = p >> 8;
    int x = p & 255;

    float kw[11];
#pragma unroll
    for (int i = 0; i < 11; ++i) kw[i] = kh[((size_t)(b * 11 + i)) * HW + p];

#pragma unroll
    for (int c = 0; c < 3; ++c) {
        const float* rp = rgb + ((size_t)(b * 3 + c)) * HW + (size_t)y * WW;
        float s = 0.0f;
#pragma unroll
        for (int i = 0; i < 11; ++i) {
            int xx = x + i - 5;
            if (xx >= 0 && xx < WW) s = fmaf(kw[i], rp[xx], s);
        }
        h[((size_t)(b * 3 + c)) * HW + p] = s;
    }
}

// ---------------------------------------------------------------------------
// Vertical pass + depth-mask composite. Writes final, blurred, mask.
// ---------------------------------------------------------------------------
__global__ __launch_bounds__(256) void vpass_compose(const float* __restrict__ h,
                                                     const float* __restrict__ kv,
                                                     const float* __restrict__ rgb,
                                                     const float* __restrict__ depth,
                                                     float* __restrict__ fin,
                                                     float* __restrict__ blur,
                                                     float* __restrict__ masko)
{
    int idx = blockIdx.x * 256 + threadIdx.x;
    int b = idx >> 16;                            // HW = 2^16
    int p = idx & (HW - 1);
    int y = p >> 8;
    int x = p & 255;

    float kw[11];
#pragma unroll
    for (int i = 0; i < 11; ++i) kw[i] = kv[((size_t)(b * 11 + i)) * HW + p];

    float d = depth[idx];
    float mk = (d > 0.2f) ? 1.0f : 0.0f;
    masko[idx] = mk;

#pragma unroll
    for (int c = 0; c < 3; ++c) {
        const float* hp = h + ((size_t)(b * 3 + c)) * HW + x;
        float s = 0.0f;
#pragma unroll
        for (int i = 0; i < 11; ++i) {
            int yy = y + i - 5;
            if (yy >= 0 && yy < HH) s = fmaf(kw[i], hp[(size_t)yy * WW], s);
        }
        size_t o = ((size_t)(b * 3 + c)) * HW + p;
        blur[o] = s;
        fin[o] = mk * rgb[o] + (1.0f - mk) * s;
    }
}

// ---------------------------------------------------------------------------
extern "C" void kernel_launch(void* const* d_in, const int* in_sizes, int n_in,
                              void* d_out, int out_size, void* d_ws, size_t ws_size,
                              hipStream_t stream)
{
    const float* rgb   = (const float*)d_in[0];
    const float* depth = (const float*)d_in[1];
    const float* w1 = (const float*)d_in[2];  const float* b1 = (const float*)d_in[3];
    const float* w2 = (const float*)d_in[4];  const float* b2 = (const float*)d_in[5];
    const float* w3 = (const float*)d_in[6];  const float* b3 = (const float*)d_in[7];
    const float* w4 = (const float*)d_in[8];  const float* b4 = (const float*)d_in[9];
    const float* w5 = (const float*)d_in[10]; const float* b5 = (const float*)d_in[11];
    const float* wh = (const float*)d_in[12]; const float* bh = (const float*)d_in[13];
    const float* wv = (const float*)d_in[14]; const float* bv = (const float*)d_in[15];

    float* out    = (float*)d_out;
    float* fin_o  = out;                    // [8,3,256,256]
    float* blur_o = out + 1572864;          // [8,3,256,256]
    float* kh_o   = out + 3145728;          // [8,11,256,256]
    float* kv_o   = out + 8912896;          // [8,11,256,256]
    float* mask_o = out + 14680064;         // [8,1,256,256]

    // --- Select batch group size G from ws_size (deterministic -> graph-safe).
    const size_t perG = (size_t)HW * 2 * (128 + 64 + 128);   // 41.9 MB per image
    const size_t wsz  = (size_t)1 * 1024 * 1024;
    int G = 1;
    if (ws_size >= 8 * perG + wsz) G = 8;
    else if (ws_size >= 4 * perG + wsz) G = 4;
    else if (ws_size >= 2 * perG + wsz) G = 2;

    char* ws = (char*)d_ws;
    const size_t szA = (size_t)G * HW * 128 * 2;
    const size_t szB = (size_t)G * HW * 64 * 2;
    const size_t szC = (size_t)G * HW * 128 * 2;
    bf16* bufA = (bf16*)ws;
    bf16* bufB = (bf16*)(ws + szA);
    bf16* bufC = (bf16*)(ws + szA + szB);
    float* hbuf = (float*)bufC;              // 6.3 MB <= szC

    bf16* wbase = (bf16*)(ws + szA + szB + szC);
    bf16* w2r  = wbase;                      // [9][64][64]
    bf16* w3r  = wbase + 36864;              // [9][128][64]
    bf16* w4r  = wbase + 110592;             // [9][128][128]
    bf16* w5r  = wbase + 258048;             // [9][64][128]
    bf16* whvr = wbase + 331776;             // [9][32][64]

    dim3 blk(256);

    // one launch for all weight reorders (graph-safe: identical work per call)
    reorder_all<<<dim3((350208 + 255) / 256), blk, 0, stream>>>(w2, w3, w4, w5, wh, wv, wbase);

    for (int b0 = 0; b0 < BB; b0 += G) {
        // conv1: COC=64, single z-slice (input taps loaded once)
        conv3x3_first64<<<dim3(4, 64 * G), blk, 0, stream>>>(rgb, depth, w1, b1, bufA, b0);
        // conv2/conv5 (COUT=64): 8 rows, 512 thr, NT=4  [R10 proven]
        conv_mfma_v3<64, 64, 4, 8, 512, 4> <<<dim3(4, 32 * G), dim3(512), 0, stream>>>(bufA, w2r, b2, bufB);
        // conv3/conv4 (COUT=128): 4 rows, 256 thr, NT=8  [R10 proven]
        conv_mfma_v3<64, 128, 8, 4, 256, 2><<<dim3(4, 64 * G), blk, 0, stream>>>(bufB, w3r, b3, bufC);
        conv_mfma_v3<128,128, 8, 4, 256, 2><<<dim3(4, 64 * G), blk, 0, stream>>>(bufC, w4r, b4, bufA);
        conv_mfma_v3<128, 64, 4, 8, 512, 4><<<dim3(4, 32 * G), dim3(512), 0, stream>>>(bufA, w5r, b5, bufB);
        head_mfma2<<<dim3(4, 64 * G), blk, 0, stream>>>(bufB, whvr, bh, bv, kh_o, kv_o, b0);
    }

    // separable blur + composite (full batch; bufC/f3 dead by now)
    hpass<<<dim3(2048), blk, 0, stream>>>(rgb, kh_o, hbuf);
    vpass_compose<<<dim3(2048), blk, 0, stream>>>(hbuf, kv_o, rgb, depth,
                                                  fin_o, blur_o, mask_o);
}